// Round 3
// baseline (138.247 us; speedup 1.0000x reference)
//
#include <hip/hip_runtime.h>
#include <math.h>

// CausalRevIN: B=16, T=8192, C=128, fp32 in/out.
// 5-pass chunked-scan decomposition:
//   P1: per-chunk sums of x and nm=1-mask
//   P2: parallel exclusive prefix over chunks (x, nm)
//   P3: per-chunk dev^2 sums using prefix offsets
//   P4: parallel exclusive prefix over chunks (dev^2)
//   P5: final normalize + clip (non-temporal output stores)
// R3: LSUB 32->8 (runtime-chosen by ws_size) for 4x occupancy; NT stores so
//     the 64 MiB output never evicts x/mask from L3.
constexpr int B = 16;
constexpr int T = 8192;
constexpr int C = 128;
constexpr int CG = C / 4;          // 32 float4 channel-groups
constexpr float STD_MIN = 1e-5f;
constexpr float MAX_VAL = 100.0f;

using f32x4 = __attribute__((ext_vector_type(4))) float;

template <int LSUB>
__device__ inline void decomp(int gtid, int& b, int& k, int& cg) {
    constexpr int NC = T / LSUB;
    cg = gtid & (CG - 1);
    k  = (gtid / CG) & (NC - 1);
    b  = gtid / (CG * NC);
}

template <int LSUB>
__global__ __launch_bounds__(256) void k_chunk_sums(
    const f32x4* __restrict__ x, const f32x4* __restrict__ mask,
    f32x4* __restrict__ sumx, f32x4* __restrict__ sumnm)
{
    constexpr int NC = T / LSUB;
    int gtid = blockIdx.x * 256 + threadIdx.x;
    int b, k, cg; decomp<LSUB>(gtid, b, k, cg);
    size_t base = (((size_t)b * T + (size_t)k * LSUB) * C) / 4 + cg;
    f32x4 sx = {0,0,0,0}, sn = {0,0,0,0};
    #pragma unroll
    for (int t = 0; t < LSUB; ++t) {
        f32x4 xv = x[base + (size_t)t * CG];
        f32x4 mv = mask[base + (size_t)t * CG];
        sx += xv;
        sn += 1.0f - mv;
    }
    size_t o = ((size_t)b * NC + k) * CG + cg;
    sumx[o]  = sx;
    sumnm[o] = sn;
}

// ---- parallel exclusive block scan over the NC dimension -------------------
template <int NCOMP>
__device__ inline void block_exscan(float* vals, int lane, int wave)
{
    float inc[NCOMP];
    #pragma unroll
    for (int j = 0; j < NCOMP; ++j) inc[j] = vals[j];
    #pragma unroll
    for (int d = 1; d < 64; d <<= 1) {
        #pragma unroll
        for (int j = 0; j < NCOMP; ++j) {
            float u = __shfl_up(inc[j], d, 64);
            if (lane >= d) inc[j] += u;
        }
    }
    __shared__ float wsum[4][NCOMP];
    if (lane == 63) {
        #pragma unroll
        for (int j = 0; j < NCOMP; ++j) wsum[wave][j] = inc[j];
    }
    __syncthreads();
    float off[NCOMP];
    #pragma unroll
    for (int j = 0; j < NCOMP; ++j) off[j] = 0.0f;
    for (int w = 0; w < wave; ++w) {
        #pragma unroll
        for (int j = 0; j < NCOMP; ++j) off[j] += wsum[w][j];
    }
    #pragma unroll
    for (int j = 0; j < NCOMP; ++j) {
        float e = __shfl_up(inc[j], 1, 64);
        vals[j] = off[j] + ((lane == 0) ? 0.0f : e);
    }
}

// thread handles NSEQ consecutive chunks: local serial + block scan of totals
template <int NSEQ>
__global__ __launch_bounds__(256) void k_prefix_two_par(
    f32x4* __restrict__ a0, f32x4* __restrict__ a1)
{
    constexpr int NC = 256 * NSEQ;
    int blk = blockIdx.x;            // b*CG + cg
    int cg = blk & (CG - 1);
    int b  = blk / CG;
    int lane = threadIdx.x & 63, wave = threadIdx.x >> 6;
    size_t obase = ((size_t)b * NC + (size_t)threadIdx.x * NSEQ) * CG + cg;
    f32x4 v0[NSEQ], v1[NSEQ];
    #pragma unroll
    for (int s = 0; s < NSEQ; ++s) {
        v0[s] = a0[obase + (size_t)s * CG];
        v1[s] = a1[obase + (size_t)s * CG];
    }
    float tot[8] = {0,0,0,0,0,0,0,0};
    #pragma unroll
    for (int s = 0; s < NSEQ; ++s) {
        #pragma unroll
        for (int j = 0; j < 4; ++j) { tot[j] += v0[s][j]; tot[4 + j] += v1[s][j]; }
    }
    block_exscan<8>(tot, lane, wave);
    f32x4 r0 = {tot[0], tot[1], tot[2], tot[3]};
    f32x4 r1 = {tot[4], tot[5], tot[6], tot[7]};
    #pragma unroll
    for (int s = 0; s < NSEQ; ++s) {
        a0[obase + (size_t)s * CG] = r0;
        a1[obase + (size_t)s * CG] = r1;
        r0 += v0[s];
        r1 += v1[s];
    }
}

template <int NSEQ>
__global__ __launch_bounds__(256) void k_prefix_one_par(f32x4* __restrict__ a0)
{
    constexpr int NC = 256 * NSEQ;
    int blk = blockIdx.x;
    int cg = blk & (CG - 1);
    int b  = blk / CG;
    int lane = threadIdx.x & 63, wave = threadIdx.x >> 6;
    size_t obase = ((size_t)b * NC + (size_t)threadIdx.x * NSEQ) * CG + cg;
    f32x4 v0[NSEQ];
    #pragma unroll
    for (int s = 0; s < NSEQ; ++s) v0[s] = a0[obase + (size_t)s * CG];
    float tot[4] = {0,0,0,0};
    #pragma unroll
    for (int s = 0; s < NSEQ; ++s) {
        #pragma unroll
        for (int j = 0; j < 4; ++j) tot[j] += v0[s][j];
    }
    block_exscan<4>(tot, lane, wave);
    f32x4 r0 = {tot[0], tot[1], tot[2], tot[3]};
    #pragma unroll
    for (int s = 0; s < NSEQ; ++s) {
        a0[obase + (size_t)s * CG] = r0;
        r0 += v0[s];
    }
}
// ---------------------------------------------------------------------------

template <int LSUB>
__global__ __launch_bounds__(256) void k_dev2_sums(
    const f32x4* __restrict__ x, const f32x4* __restrict__ mask,
    const f32x4* __restrict__ psumx, const f32x4* __restrict__ psumnm,
    f32x4* __restrict__ sumd2)
{
    constexpr int NC = T / LSUB;
    int gtid = blockIdx.x * 256 + threadIdx.x;
    int b, k, cg; decomp<LSUB>(gtid, b, k, cg);
    size_t base = (((size_t)b * T + (size_t)k * LSUB) * C) / 4 + cg;
    size_t o = ((size_t)b * NC + k) * CG + cg;
    f32x4 px = psumx[o];
    f32x4 pn = psumnm[o];
    f32x4 sx = {0,0,0,0}, sn = {0,0,0,0}, sd = {0,0,0,0};
    #pragma unroll
    for (int t = 0; t < LSUB; ++t) {
        f32x4 xv = x[base + (size_t)t * CG];
        f32x4 mv = mask[base + (size_t)t * CG];
        f32x4 nm = 1.0f - mv;
        sx += xv;
        sn += nm;
        f32x4 n = pn + sn;
        f32x4 neff;
        #pragma unroll
        for (int j = 0; j < 4; ++j) neff[j] = (n[j] == 0.0f) ? 1.0f : n[j];
        f32x4 mean = (px + sx) / neff;
        f32x4 d = (xv - mean) * nm;
        sd += d * d;
    }
    sumd2[o] = sd;
}

template <int LSUB>
__global__ __launch_bounds__(256) void k_finalize(
    const f32x4* __restrict__ x, const f32x4* __restrict__ mask,
    const f32x4* __restrict__ psumx, const f32x4* __restrict__ psumnm,
    const f32x4* __restrict__ psumd2, f32x4* __restrict__ out)
{
    constexpr int NC = T / LSUB;
    int gtid = blockIdx.x * 256 + threadIdx.x;
    int b, k, cg; decomp<LSUB>(gtid, b, k, cg);
    size_t base = (((size_t)b * T + (size_t)k * LSUB) * C) / 4 + cg;
    size_t o = ((size_t)b * NC + k) * CG + cg;
    f32x4 px = psumx[o];
    f32x4 pn = psumnm[o];
    f32x4 pd = psumd2[o];
    f32x4 sx = {0,0,0,0}, sn = {0,0,0,0}, sd = {0,0,0,0};
    #pragma unroll
    for (int t = 0; t < LSUB; ++t) {
        f32x4 xv = x[base + (size_t)t * CG];
        f32x4 mv = mask[base + (size_t)t * CG];
        f32x4 nm = 1.0f - mv;
        sx += xv;
        sn += nm;
        f32x4 n = pn + sn;
        f32x4 ov;
        #pragma unroll
        for (int j = 0; j < 4; ++j) {
            float neff = (n[j] == 0.0f) ? 1.0f : n[j];
            float mean = (px[j] + sx[j]) / neff;
            float d    = (xv[j] - mean) * nm[j];
            sd[j] += d * d;
            float s = sqrtf((pd[j] + sd[j]) / neff);
            s = (s > STD_MIN) ? s : 1.0f;
            float v = (xv[j] - mean) / s;
            ov[j] = fminf(fmaxf(v, -MAX_VAL), MAX_VAL);
        }
        // non-temporal: stream output past caches, keep x/mask L3-resident
        __builtin_nontemporal_store(ov, &out[base + (size_t)t * CG]);
    }
}

template <int LSUB>
static void run_all(const f32x4* x, const f32x4* mask, f32x4* out,
                    void* d_ws, hipStream_t stream)
{
    constexpr int NC = T / LSUB;
    constexpr int NSEQ = NC / 256;
    size_t arr_elems = (size_t)B * NC * C;   // floats per ws array
    f32x4* sumx  = (f32x4*)d_ws;
    f32x4* sumnm = (f32x4*)((float*)d_ws + arr_elems);
    f32x4* sumd2 = (f32x4*)((float*)d_ws + 2 * arr_elems);

    int main_blocks = B * NC * CG / 256;
    int scan_blocks = B * CG;                // 512

    k_chunk_sums<LSUB><<<main_blocks, 256, 0, stream>>>(x, mask, sumx, sumnm);
    k_prefix_two_par<NSEQ><<<scan_blocks, 256, 0, stream>>>(sumx, sumnm);
    k_dev2_sums<LSUB><<<main_blocks, 256, 0, stream>>>(x, mask, sumx, sumnm, sumd2);
    k_prefix_one_par<NSEQ><<<scan_blocks, 256, 0, stream>>>(sumd2);
    k_finalize<LSUB><<<main_blocks, 256, 0, stream>>>(x, mask, sumx, sumnm, sumd2, out);
}

extern "C" void kernel_launch(void* const* d_in, const int* in_sizes, int n_in,
                              void* d_out, int out_size, void* d_ws, size_t ws_size,
                              hipStream_t stream) {
    const f32x4* x    = (const f32x4*)d_in[0];
    const f32x4* mask = (const f32x4*)d_in[1];
    f32x4* out = (f32x4*)d_out;

    size_t need8  = 3ull * B * (T / 8)  * C * sizeof(float);   // 24 MiB
    size_t need16 = 3ull * B * (T / 16) * C * sizeof(float);   // 12 MiB

    if (ws_size >= need8)       run_all<8>(x, mask, out, d_ws, stream);
    else if (ws_size >= need16) run_all<16>(x, mask, out, d_ws, stream);
    else                        run_all<32>(x, mask, out, d_ws, stream);
}

// Round 4
// 111.876 us; speedup vs baseline: 1.2357x; 1.2357x over previous
//
#include <hip/hip_runtime.h>
#include <math.h>

// CausalRevIN: B=16, T=8192, C=128, fp32.
// R4: LDS-tiled passes — all HBM access is linear/dense (wave instr = 1 KiB
// contiguous), column math from LDS. Block = 32 t-rows x 128 ch tile.
// 5 kernels: P1 chunk sums -> P2 scan -> P3 dev2 sums -> P4 scan -> P5 output.
constexpr int B = 16;
constexpr int T = 8192;
constexpr int C = 128;
constexpr int CG = C / 4;      // 32 float4 channel-groups
constexpr int TB = 32;         // t-rows per block tile
constexpr int NC = T / TB;     // 256 chunks per batch
constexpr int SUBS = 8;        // sub-chunks (threads 256 = SUBS*CG)
constexpr int RPT = TB / SUBS; // 4 rows per thread
constexpr float STD_MIN = 1e-5f;
constexpr float MAX_VAL = 100.0f;

using f32x4 = __attribute__((ext_vector_type(4))) float;

__device__ inline f32x4 sel_neff(f32x4 n) {
    f32x4 r;
    #pragma unroll
    for (int j = 0; j < 4; ++j) r[j] = (n[j] == 0.0f) ? 1.0f : n[j];
    return r;
}

// ---------------- P1: per-chunk (32-row) sums of x and nm ------------------
__global__ __launch_bounds__(256) void k_pass1(
    const f32x4* __restrict__ x, const f32x4* __restrict__ mask,
    f32x4* __restrict__ sumx, f32x4* __restrict__ sumnm)
{
    __shared__ f32x4 tx[TB * CG], tm[TB * CG];     // 16 KiB + 16 KiB
    __shared__ f32x4 p0[SUBS][CG], p1[SUBS][CG];   // 4 KiB + 4 KiB
    int tid = threadIdx.x, cg = tid & 31, sub = tid >> 5;
    int blk = blockIdx.x, b = blk >> 8, kb = blk & 255;
    size_t gbase = (size_t)(b * T + kb * TB) * CG;
    #pragma unroll
    for (int i = 0; i < 4; ++i) {
        int idx = i * 256 + tid;
        tx[idx] = x[gbase + idx];
        tm[idx] = mask[gbase + idx];
    }
    __syncthreads();
    f32x4 sx = {0,0,0,0}, sn = {0,0,0,0};
    #pragma unroll
    for (int r = 0; r < RPT; ++r) {
        int row = sub * RPT + r;
        sx += tx[row * CG + cg];
        sn += 1.0f - tm[row * CG + cg];
    }
    p0[sub][cg] = sx; p1[sub][cg] = sn;
    __syncthreads();
    if (sub == 0) {
        f32x4 ax = {0,0,0,0}, an = {0,0,0,0};
        #pragma unroll
        for (int s = 0; s < SUBS; ++s) { ax += p0[s][cg]; an += p1[s][cg]; }
        size_t o = ((size_t)b * NC + kb) * CG + cg;
        sumx[o] = ax; sumnm[o] = an;
    }
}

// ---------------- parallel exclusive block scan over NC=256 ----------------
template <int NCOMP>
__device__ inline void block_exscan(float* vals, int lane, int wave)
{
    float inc[NCOMP];
    #pragma unroll
    for (int j = 0; j < NCOMP; ++j) inc[j] = vals[j];
    #pragma unroll
    for (int d = 1; d < 64; d <<= 1) {
        #pragma unroll
        for (int j = 0; j < NCOMP; ++j) {
            float u = __shfl_up(inc[j], d, 64);
            if (lane >= d) inc[j] += u;
        }
    }
    __shared__ float wsum[4][NCOMP];
    if (lane == 63) {
        #pragma unroll
        for (int j = 0; j < NCOMP; ++j) wsum[wave][j] = inc[j];
    }
    __syncthreads();
    float off[NCOMP];
    #pragma unroll
    for (int j = 0; j < NCOMP; ++j) off[j] = 0.0f;
    for (int w = 0; w < wave; ++w) {
        #pragma unroll
        for (int j = 0; j < NCOMP; ++j) off[j] += wsum[w][j];
    }
    #pragma unroll
    for (int j = 0; j < NCOMP; ++j) {
        float e = __shfl_up(inc[j], 1, 64);
        vals[j] = off[j] + ((lane == 0) ? 0.0f : e);
    }
}

__global__ __launch_bounds__(256) void k_scan2(f32x4* __restrict__ a0,
                                               f32x4* __restrict__ a1)
{
    int blk = blockIdx.x, cg = blk & 31, b = blk >> 5;
    int k = threadIdx.x, lane = k & 63, wave = k >> 6;
    size_t o = ((size_t)b * NC + k) * CG + cg;
    f32x4 v0 = a0[o], v1 = a1[o];
    float vals[8] = {v0[0],v0[1],v0[2],v0[3],v1[0],v1[1],v1[2],v1[3]};
    block_exscan<8>(vals, lane, wave);
    a0[o] = (f32x4){vals[0],vals[1],vals[2],vals[3]};
    a1[o] = (f32x4){vals[4],vals[5],vals[6],vals[7]};
}

__global__ __launch_bounds__(256) void k_scan1(f32x4* __restrict__ a0)
{
    int blk = blockIdx.x, cg = blk & 31, b = blk >> 5;
    int k = threadIdx.x, lane = k & 63, wave = k >> 6;
    size_t o = ((size_t)b * NC + k) * CG + cg;
    f32x4 v0 = a0[o];
    float vals[4] = {v0[0],v0[1],v0[2],v0[3]};
    block_exscan<4>(vals, lane, wave);
    a0[o] = (f32x4){vals[0],vals[1],vals[2],vals[3]};
}

// ---------------- P3: per-chunk dev^2 sums ---------------------------------
__global__ __launch_bounds__(256) void k_pass3(
    const f32x4* __restrict__ x, const f32x4* __restrict__ mask,
    const f32x4* __restrict__ psumx, const f32x4* __restrict__ psumnm,
    f32x4* __restrict__ sumd2)
{
    __shared__ f32x4 tx[TB * CG], tm[TB * CG];
    __shared__ f32x4 p0[SUBS][CG], p1[SUBS][CG];
    int tid = threadIdx.x, cg = tid & 31, sub = tid >> 5;
    int blk = blockIdx.x, b = blk >> 8, kb = blk & 255;
    size_t gbase = (size_t)(b * T + kb * TB) * CG;
    #pragma unroll
    for (int i = 0; i < 4; ++i) {
        int idx = i * 256 + tid;
        tx[idx] = x[gbase + idx];
        tm[idx] = mask[gbase + idx];
    }
    __syncthreads();
    // sweep1: per-thread totals
    f32x4 ax = {0,0,0,0}, an = {0,0,0,0};
    #pragma unroll
    for (int r = 0; r < RPT; ++r) {
        int row = sub * RPT + r;
        ax += tx[row * CG + cg];
        an += 1.0f - tm[row * CG + cg];
    }
    p0[sub][cg] = ax; p1[sub][cg] = an;
    __syncthreads();
    size_t o = ((size_t)b * NC + kb) * CG + cg;
    f32x4 rx = psumx[o], rn = psumnm[o];
    for (int s = 0; s < sub; ++s) { rx += p0[s][cg]; rn += p1[s][cg]; }
    // sweep2: running mean -> dev^2 sums
    f32x4 sd = {0,0,0,0};
    #pragma unroll
    for (int r = 0; r < RPT; ++r) {
        int row = sub * RPT + r;
        f32x4 xv = tx[row * CG + cg];
        f32x4 nm = 1.0f - tm[row * CG + cg];
        rx += xv; rn += nm;
        f32x4 mean = rx / sel_neff(rn);
        f32x4 d = (xv - mean) * nm;
        sd += d * d;
    }
    __syncthreads();            // before reusing p0
    p0[sub][cg] = sd;
    __syncthreads();
    if (sub == 0) {
        f32x4 ad = {0,0,0,0};
        #pragma unroll
        for (int s = 0; s < SUBS; ++s) ad += p0[s][cg];
        sumd2[o] = ad;
    }
}

// ---------------- P5: final normalize + clip, dense NT output --------------
__global__ __launch_bounds__(256) void k_pass5(
    const f32x4* __restrict__ x, const f32x4* __restrict__ mask,
    const f32x4* __restrict__ psumx, const f32x4* __restrict__ psumnm,
    const f32x4* __restrict__ psumd2, f32x4* __restrict__ out)
{
    __shared__ f32x4 tx[TB * CG], tm[TB * CG];
    __shared__ f32x4 p0[SUBS][CG], p1[SUBS][CG];
    int tid = threadIdx.x, cg = tid & 31, sub = tid >> 5;
    int blk = blockIdx.x, b = blk >> 8, kb = blk & 255;
    size_t gbase = (size_t)(b * T + kb * TB) * CG;
    #pragma unroll
    for (int i = 0; i < 4; ++i) {
        int idx = i * 256 + tid;
        tx[idx] = x[gbase + idx];
        tm[idx] = mask[gbase + idx];
    }
    __syncthreads();
    // sweep1: per-thread x/nm totals -> exclusive offsets
    f32x4 ax = {0,0,0,0}, an = {0,0,0,0};
    #pragma unroll
    for (int r = 0; r < RPT; ++r) {
        int row = sub * RPT + r;
        ax += tx[row * CG + cg];
        an += 1.0f - tm[row * CG + cg];
    }
    p0[sub][cg] = ax; p1[sub][cg] = an;
    __syncthreads();
    size_t o = ((size_t)b * NC + kb) * CG + cg;
    f32x4 rx0 = psumx[o], rn0 = psumnm[o];
    for (int s = 0; s < sub; ++s) { rx0 += p0[s][cg]; rn0 += p1[s][cg]; }
    // sweep2: per-thread dev^2 totals (identical expressions to P3)
    f32x4 rx = rx0, rn = rn0, sd = {0,0,0,0};
    #pragma unroll
    for (int r = 0; r < RPT; ++r) {
        int row = sub * RPT + r;
        f32x4 xv = tx[row * CG + cg];
        f32x4 nm = 1.0f - tm[row * CG + cg];
        rx += xv; rn += nm;
        f32x4 mean = rx / sel_neff(rn);
        f32x4 d = (xv - mean) * nm;
        sd += d * d;
    }
    __syncthreads();            // before reusing p0
    p0[sub][cg] = sd;
    __syncthreads();
    f32x4 rd = psumd2[o];
    for (int s = 0; s < sub; ++s) rd += p0[s][cg];
    // sweep3: output, written back into the x tile (exclusive ownership)
    rx = rx0; rn = rn0;
    #pragma unroll
    for (int r = 0; r < RPT; ++r) {
        int row = sub * RPT + r;
        f32x4 xv = tx[row * CG + cg];
        f32x4 nm = 1.0f - tm[row * CG + cg];
        rx += xv; rn += nm;
        f32x4 neff = sel_neff(rn);
        f32x4 mean = rx / neff;
        f32x4 d = (xv - mean) * nm;
        rd += d * d;
        f32x4 ov;
        #pragma unroll
        for (int j = 0; j < 4; ++j) {
            float s = sqrtf(rd[j] / neff[j]);
            s = (s > STD_MIN) ? s : 1.0f;
            float v = (xv[j] - mean[j]) / s;
            ov[j] = fminf(fmaxf(v, -MAX_VAL), MAX_VAL);
        }
        tx[row * CG + cg] = ov;
    }
    __syncthreads();
    #pragma unroll
    for (int i = 0; i < 4; ++i) {
        int idx = i * 256 + tid;
        __builtin_nontemporal_store(tx[idx], &out[gbase + idx]);
    }
}

extern "C" void kernel_launch(void* const* d_in, const int* in_sizes, int n_in,
                              void* d_out, int out_size, void* d_ws, size_t ws_size,
                              hipStream_t stream) {
    const f32x4* x    = (const f32x4*)d_in[0];
    const f32x4* mask = (const f32x4*)d_in[1];
    f32x4* out = (f32x4*)d_out;

    // ws: 3 arrays of [B][NC][C] floats (2 MiB each)
    size_t arr_elems = (size_t)B * NC * C;
    f32x4* sumx  = (f32x4*)d_ws;
    f32x4* sumnm = (f32x4*)((float*)d_ws + arr_elems);
    f32x4* sumd2 = (f32x4*)((float*)d_ws + 2 * arr_elems);

    int big_blocks  = B * T / TB;   // 4096
    int scan_blocks = B * CG;       // 512

    k_pass1<<<big_blocks, 256, 0, stream>>>(x, mask, sumx, sumnm);
    k_scan2<<<scan_blocks, 256, 0, stream>>>(sumx, sumnm);
    k_pass3<<<big_blocks, 256, 0, stream>>>(x, mask, sumx, sumnm, sumd2);
    k_scan1<<<scan_blocks, 256, 0, stream>>>(sumd2);
    k_pass5<<<big_blocks, 256, 0, stream>>>(x, mask, sumx, sumnm, sumd2, out);
}

// Round 5
// 89.028 us; speedup vs baseline: 1.5528x; 1.2566x over previous
//
#include <hip/hip_runtime.h>
#include <math.h>

// CausalRevIN: B=16, T=8192, C=128, fp32.
// R5: (a) mask compressed to nm-bytes in ws (16MB) so total L3 footprint
//     (~214MB) fits the 256MB MALL -> steady-state HBM ~= output writes only;
//     (b) fast rcp/sqrt intrinsics (absmax headroom 0.016 vs 2.0);
//     (c) P5 caches mean/dsq/inv_neff in registers, sweep3 does no recompute.
constexpr int B = 16;
constexpr int T = 8192;
constexpr int C = 128;
constexpr int CG = C / 4;      // 32 float4 channel-groups
constexpr int TB = 32;         // t-rows per block tile
constexpr int NC = T / TB;     // 256 chunks per batch
constexpr int SUBS = 8;        // sub-chunks (256 threads = SUBS*CG)
constexpr int RPT = TB / SUBS; // 4 rows per thread
constexpr float STD_MIN = 1e-5f;
constexpr float MAX_VAL = 100.0f;

using f32x4 = __attribute__((ext_vector_type(4))) float;

__device__ inline f32x4 sel_neff(f32x4 n) {
    f32x4 r;
    #pragma unroll
    for (int j = 0; j < 4; ++j) r[j] = (n[j] == 0.0f) ? 1.0f : n[j];
    return r;
}
__device__ inline f32x4 rcp4(f32x4 a) {
    f32x4 r;
    #pragma unroll
    for (int j = 0; j < 4; ++j) r[j] = __builtin_amdgcn_rcpf(a[j]);
    return r;
}
__device__ inline f32x4 sqrt4(f32x4 a) {
    f32x4 r;
    #pragma unroll
    for (int j = 0; j < 4; ++j) r[j] = __builtin_amdgcn_sqrtf(a[j]);
    return r;
}
__device__ inline f32x4 decode_nm(unsigned w) {
    f32x4 r;
    #pragma unroll
    for (int j = 0; j < 4; ++j) r[j] = (float)((w >> (8 * j)) & 0xffu);
    return r;
}

// ---------------- P1: per-chunk sums of x and nm; emit nm bytes ------------
template <bool BYTES>
__global__ __launch_bounds__(256) void k_pass1(
    const f32x4* __restrict__ x, const f32x4* __restrict__ mask,
    f32x4* __restrict__ sumx, f32x4* __restrict__ sumnm,
    unsigned* __restrict__ nmb)
{
    __shared__ f32x4 tx[TB * CG], tm[TB * CG];
    __shared__ f32x4 p0[SUBS][CG], p1[SUBS][CG];
    int tid = threadIdx.x, cg = tid & 31, sub = tid >> 5;
    int blk = blockIdx.x, b = blk >> 8, kb = blk & 255;
    size_t gbase = (size_t)(b * T + kb * TB) * CG;
    #pragma unroll
    for (int i = 0; i < 4; ++i) {
        int idx = i * 256 + tid;
        f32x4 xv = x[gbase + idx];
        f32x4 mv = mask[gbase + idx];
        tx[idx] = xv;
        tm[idx] = mv;
        if (BYTES) {
            unsigned w = (unsigned)(1.0f - mv[0])
                       | ((unsigned)(1.0f - mv[1]) << 8)
                       | ((unsigned)(1.0f - mv[2]) << 16)
                       | ((unsigned)(1.0f - mv[3]) << 24);
            nmb[gbase + idx] = w;
        }
    }
    __syncthreads();
    f32x4 sx = {0,0,0,0}, sn = {0,0,0,0};
    #pragma unroll
    for (int r = 0; r < RPT; ++r) {
        int row = sub * RPT + r;
        sx += tx[row * CG + cg];
        sn += 1.0f - tm[row * CG + cg];
    }
    p0[sub][cg] = sx; p1[sub][cg] = sn;
    __syncthreads();
    if (sub == 0) {
        f32x4 ax = {0,0,0,0}, an = {0,0,0,0};
        #pragma unroll
        for (int s = 0; s < SUBS; ++s) { ax += p0[s][cg]; an += p1[s][cg]; }
        size_t o = ((size_t)b * NC + kb) * CG + cg;
        sumx[o] = ax; sumnm[o] = an;
    }
}

// ---------------- parallel exclusive block scan over NC=256 ----------------
template <int NCOMP>
__device__ inline void block_exscan(float* vals, int lane, int wave)
{
    float inc[NCOMP];
    #pragma unroll
    for (int j = 0; j < NCOMP; ++j) inc[j] = vals[j];
    #pragma unroll
    for (int d = 1; d < 64; d <<= 1) {
        #pragma unroll
        for (int j = 0; j < NCOMP; ++j) {
            float u = __shfl_up(inc[j], d, 64);
            if (lane >= d) inc[j] += u;
        }
    }
    __shared__ float wsum[4][NCOMP];
    if (lane == 63) {
        #pragma unroll
        for (int j = 0; j < NCOMP; ++j) wsum[wave][j] = inc[j];
    }
    __syncthreads();
    float off[NCOMP];
    #pragma unroll
    for (int j = 0; j < NCOMP; ++j) off[j] = 0.0f;
    for (int w = 0; w < wave; ++w) {
        #pragma unroll
        for (int j = 0; j < NCOMP; ++j) off[j] += wsum[w][j];
    }
    #pragma unroll
    for (int j = 0; j < NCOMP; ++j) {
        float e = __shfl_up(inc[j], 1, 64);
        vals[j] = off[j] + ((lane == 0) ? 0.0f : e);
    }
}

__global__ __launch_bounds__(256) void k_scan2(f32x4* __restrict__ a0,
                                               f32x4* __restrict__ a1)
{
    int blk = blockIdx.x, cg = blk & 31, b = blk >> 5;
    int k = threadIdx.x, lane = k & 63, wave = k >> 6;
    size_t o = ((size_t)b * NC + k) * CG + cg;
    f32x4 v0 = a0[o], v1 = a1[o];
    float vals[8] = {v0[0],v0[1],v0[2],v0[3],v1[0],v1[1],v1[2],v1[3]};
    block_exscan<8>(vals, lane, wave);
    a0[o] = (f32x4){vals[0],vals[1],vals[2],vals[3]};
    a1[o] = (f32x4){vals[4],vals[5],vals[6],vals[7]};
}

__global__ __launch_bounds__(256) void k_scan1(f32x4* __restrict__ a0)
{
    int blk = blockIdx.x, cg = blk & 31, b = blk >> 5;
    int k = threadIdx.x, lane = k & 63, wave = k >> 6;
    size_t o = ((size_t)b * NC + k) * CG + cg;
    f32x4 v0 = a0[o];
    float vals[4] = {v0[0],v0[1],v0[2],v0[3]};
    block_exscan<4>(vals, lane, wave);
    a0[o] = (f32x4){vals[0],vals[1],vals[2],vals[3]};
}

// ---------------- P3: per-chunk dev^2 sums ---------------------------------
template <bool BYTES>
__global__ __launch_bounds__(256) void k_pass3(
    const f32x4* __restrict__ x, const f32x4* __restrict__ mask,
    const unsigned* __restrict__ nmb,
    const f32x4* __restrict__ psumx, const f32x4* __restrict__ psumnm,
    f32x4* __restrict__ sumd2)
{
    __shared__ f32x4 tx[TB * CG];
    __shared__ unsigned nmt[BYTES ? TB * CG : 1];
    __shared__ f32x4 tm[BYTES ? 1 : TB * CG];
    __shared__ f32x4 p0[SUBS][CG], p1[SUBS][CG];
    int tid = threadIdx.x, cg = tid & 31, sub = tid >> 5;
    int blk = blockIdx.x, b = blk >> 8, kb = blk & 255;
    size_t gbase = (size_t)(b * T + kb * TB) * CG;
    #pragma unroll
    for (int i = 0; i < 4; ++i) {
        int idx = i * 256 + tid;
        tx[idx] = x[gbase + idx];
        if (BYTES) nmt[idx] = nmb[gbase + idx];
        else       tm[idx]  = mask[gbase + idx];
    }
    __syncthreads();
    f32x4 ax = {0,0,0,0}, an = {0,0,0,0};
    #pragma unroll
    for (int r = 0; r < RPT; ++r) {
        int row = sub * RPT + r;
        f32x4 nm = BYTES ? decode_nm(nmt[row * CG + cg])
                         : (1.0f - tm[row * CG + cg]);
        ax += tx[row * CG + cg];
        an += nm;
    }
    p0[sub][cg] = ax; p1[sub][cg] = an;
    __syncthreads();
    size_t o = ((size_t)b * NC + kb) * CG + cg;
    f32x4 rx = psumx[o], rn = psumnm[o];
    for (int s = 0; s < sub; ++s) { rx += p0[s][cg]; rn += p1[s][cg]; }
    f32x4 sd = {0,0,0,0};
    #pragma unroll
    for (int r = 0; r < RPT; ++r) {
        int row = sub * RPT + r;
        f32x4 xv = tx[row * CG + cg];
        f32x4 nm = BYTES ? decode_nm(nmt[row * CG + cg])
                         : (1.0f - tm[row * CG + cg]);
        rx += xv; rn += nm;
        f32x4 mean = rx * rcp4(sel_neff(rn));
        f32x4 d = (xv - mean) * nm;
        sd += d * d;
    }
    __syncthreads();
    p0[sub][cg] = sd;
    __syncthreads();
    if (sub == 0) {
        f32x4 ad = {0,0,0,0};
        #pragma unroll
        for (int s = 0; s < SUBS; ++s) ad += p0[s][cg];
        sumd2[o] = ad;
    }
}

// ---------------- P5: final normalize + clip -------------------------------
template <bool BYTES>
__global__ __launch_bounds__(256) void k_pass5(
    const f32x4* __restrict__ x, const f32x4* __restrict__ mask,
    const unsigned* __restrict__ nmb,
    const f32x4* __restrict__ psumx, const f32x4* __restrict__ psumnm,
    const f32x4* __restrict__ psumd2, f32x4* __restrict__ out)
{
    __shared__ f32x4 tx[TB * CG];
    __shared__ unsigned nmt[BYTES ? TB * CG : 1];
    __shared__ f32x4 tm[BYTES ? 1 : TB * CG];
    __shared__ f32x4 p0[SUBS][CG], p1[SUBS][CG];
    int tid = threadIdx.x, cg = tid & 31, sub = tid >> 5;
    int blk = blockIdx.x, b = blk >> 8, kb = blk & 255;
    size_t gbase = (size_t)(b * T + kb * TB) * CG;
    #pragma unroll
    for (int i = 0; i < 4; ++i) {
        int idx = i * 256 + tid;
        tx[idx] = x[gbase + idx];
        if (BYTES) nmt[idx] = nmb[gbase + idx];
        else       tm[idx]  = mask[gbase + idx];
    }
    __syncthreads();
    // sweep1: per-thread x/nm totals -> exclusive offsets
    f32x4 ax = {0,0,0,0}, an = {0,0,0,0};
    #pragma unroll
    for (int r = 0; r < RPT; ++r) {
        int row = sub * RPT + r;
        f32x4 nm = BYTES ? decode_nm(nmt[row * CG + cg])
                         : (1.0f - tm[row * CG + cg]);
        ax += tx[row * CG + cg];
        an += nm;
    }
    p0[sub][cg] = ax; p1[sub][cg] = an;
    __syncthreads();
    size_t o = ((size_t)b * NC + kb) * CG + cg;
    f32x4 rx = psumx[o], rn = psumnm[o];
    for (int s = 0; s < sub; ++s) { rx += p0[s][cg]; rn += p1[s][cg]; }
    // sweep2: running mean -> per-row mean/dsq/inv_neff cached in registers
    f32x4 meanr[RPT], dsqr[RPT], invnr[RPT];
    f32x4 sd = {0,0,0,0};
    #pragma unroll
    for (int r = 0; r < RPT; ++r) {
        int row = sub * RPT + r;
        f32x4 xv = tx[row * CG + cg];
        f32x4 nm = BYTES ? decode_nm(nmt[row * CG + cg])
                         : (1.0f - tm[row * CG + cg]);
        rx += xv; rn += nm;
        f32x4 inv = rcp4(sel_neff(rn));
        f32x4 m = rx * inv;
        f32x4 d = (xv - m) * nm;
        f32x4 q = d * d;
        sd += q;
        meanr[r] = m; dsqr[r] = q; invnr[r] = inv;
    }
    __syncthreads();            // before reusing p0
    p0[sub][cg] = sd;
    __syncthreads();
    f32x4 rd = psumd2[o];
    for (int s = 0; s < sub; ++s) rd += p0[s][cg];
    // sweep3: finalize from cached registers, write into tx in place
    #pragma unroll
    for (int r = 0; r < RPT; ++r) {
        int row = sub * RPT + r;
        f32x4 xv = tx[row * CG + cg];
        rd += dsqr[r];
        f32x4 s = sqrt4(rd * invnr[r]);
        f32x4 ov;
        #pragma unroll
        for (int j = 0; j < 4; ++j) {
            float invs = (s[j] > STD_MIN) ? __builtin_amdgcn_rcpf(s[j]) : 1.0f;
            float v = (xv[j] - meanr[r][j]) * invs;
            ov[j] = fminf(fmaxf(v, -MAX_VAL), MAX_VAL);
        }
        tx[row * CG + cg] = ov;
    }
    __syncthreads();
    #pragma unroll
    for (int i = 0; i < 4; ++i) {
        int idx = i * 256 + tid;
        __builtin_nontemporal_store(tx[idx], &out[gbase + idx]);
    }
}

template <bool BYTES>
static void run_all(const f32x4* x, const f32x4* mask, f32x4* out,
                    void* d_ws, hipStream_t stream)
{
    size_t arr_elems = (size_t)B * NC * C;   // floats per scan array (512K)
    f32x4* sumx  = (f32x4*)d_ws;
    f32x4* sumnm = (f32x4*)((float*)d_ws + arr_elems);
    f32x4* sumd2 = (f32x4*)((float*)d_ws + 2 * arr_elems);
    unsigned* nmb = (unsigned*)((float*)d_ws + 3 * arr_elems);

    int big_blocks  = B * T / TB;   // 4096
    int scan_blocks = B * CG;       // 512

    k_pass1<BYTES><<<big_blocks, 256, 0, stream>>>(x, mask, sumx, sumnm, nmb);
    k_scan2<<<scan_blocks, 256, 0, stream>>>(sumx, sumnm);
    k_pass3<BYTES><<<big_blocks, 256, 0, stream>>>(x, mask, nmb, sumx, sumnm, sumd2);
    k_scan1<<<scan_blocks, 256, 0, stream>>>(sumd2);
    k_pass5<BYTES><<<big_blocks, 256, 0, stream>>>(x, mask, nmb, sumx, sumnm, sumd2, out);
}

extern "C" void kernel_launch(void* const* d_in, const int* in_sizes, int n_in,
                              void* d_out, int out_size, void* d_ws, size_t ws_size,
                              hipStream_t stream) {
    const f32x4* x    = (const f32x4*)d_in[0];
    const f32x4* mask = (const f32x4*)d_in[1];
    f32x4* out = (f32x4*)d_out;

    size_t need = 3ull * B * NC * C * sizeof(float)      // 6 MiB scan arrays
                + (size_t)B * T * CG * sizeof(unsigned); // 16 MiB nm bytes

    if (ws_size >= need) run_all<true >(x, mask, out, d_ws, stream);
    else                 run_all<false>(x, mask, out, d_ws, stream);
}

// Round 6
// 87.261 us; speedup vs baseline: 1.5843x; 1.0203x over previous
//
#include <hip/hip_runtime.h>
#include <math.h>

// CausalRevIN: B=16, T=8192, C=128, fp32.
// R6: pure streaming passes (no LDS staging — R2's dev2 structure, which ran
// 128MB L3-warm in ~10us) + R5's residency control (nm-bytes 16MB, NT output
// stores). Thread owns one f32x4 column x 32 rows; running state in regs.
constexpr int B = 16;
constexpr int T = 8192;
constexpr int C = 128;
constexpr int CG = C / 4;      // 32 float4 channel-groups
constexpr int LSUB = 32;       // t-rows per chunk (thread-serial)
constexpr int NC = T / LSUB;   // 256 chunks per batch == scan blockDim
constexpr float STD_MIN = 1e-5f;
constexpr float MAX_VAL = 100.0f;

using f32x4 = __attribute__((ext_vector_type(4))) float;

__device__ inline f32x4 sel_neff(f32x4 n) {
    f32x4 r;
    #pragma unroll
    for (int j = 0; j < 4; ++j) r[j] = (n[j] == 0.0f) ? 1.0f : n[j];
    return r;
}
__device__ inline f32x4 rcp4(f32x4 a) {
    f32x4 r;
    #pragma unroll
    for (int j = 0; j < 4; ++j) r[j] = __builtin_amdgcn_rcpf(a[j]);
    return r;
}
__device__ inline f32x4 sqrt4(f32x4 a) {
    f32x4 r;
    #pragma unroll
    for (int j = 0; j < 4; ++j) r[j] = __builtin_amdgcn_sqrtf(a[j]);
    return r;
}
__device__ inline f32x4 decode_nm(unsigned w) {
    f32x4 r;
    #pragma unroll
    for (int j = 0; j < 4; ++j) r[j] = (float)((w >> (8 * j)) & 0xffu);
    return r;
}

__device__ inline void decomp(int gtid, int& b, int& k, int& cg) {
    cg = gtid & (CG - 1);
    k  = (gtid / CG) & (NC - 1);
    b  = gtid / (CG * NC);
}

// ---------------- P1: per-chunk sums of x and nm; emit nm bytes ------------
template <bool BYTES>
__global__ __launch_bounds__(256) void k_pass1(
    const f32x4* __restrict__ x, const f32x4* __restrict__ mask,
    f32x4* __restrict__ sumx, f32x4* __restrict__ sumnm,
    unsigned* __restrict__ nmb)
{
    int gtid = blockIdx.x * 256 + threadIdx.x;
    int b, k, cg; decomp(gtid, b, k, cg);
    size_t base = ((size_t)b * T + (size_t)k * LSUB) * CG + cg;
    f32x4 sx = {0,0,0,0}, sn = {0,0,0,0};
    #pragma unroll 8
    for (int t = 0; t < LSUB; ++t) {
        f32x4 xv = x[base + (size_t)t * CG];
        f32x4 mv = mask[base + (size_t)t * CG];
        f32x4 nm = 1.0f - mv;
        if (BYTES) {
            unsigned w = (unsigned)nm[0] | ((unsigned)nm[1] << 8)
                       | ((unsigned)nm[2] << 16) | ((unsigned)nm[3] << 24);
            nmb[base + (size_t)t * CG] = w;
        }
        sx += xv;
        sn += nm;
    }
    size_t o = ((size_t)b * NC + k) * CG + cg;
    sumx[o]  = sx;
    sumnm[o] = sn;
}

// ---------------- parallel exclusive block scan over NC=256 ----------------
template <int NCOMP>
__device__ inline void block_exscan(float* vals, int lane, int wave)
{
    float inc[NCOMP];
    #pragma unroll
    for (int j = 0; j < NCOMP; ++j) inc[j] = vals[j];
    #pragma unroll
    for (int d = 1; d < 64; d <<= 1) {
        #pragma unroll
        for (int j = 0; j < NCOMP; ++j) {
            float u = __shfl_up(inc[j], d, 64);
            if (lane >= d) inc[j] += u;
        }
    }
    __shared__ float wsum[4][NCOMP];
    if (lane == 63) {
        #pragma unroll
        for (int j = 0; j < NCOMP; ++j) wsum[wave][j] = inc[j];
    }
    __syncthreads();
    float off[NCOMP];
    #pragma unroll
    for (int j = 0; j < NCOMP; ++j) off[j] = 0.0f;
    for (int w = 0; w < wave; ++w) {
        #pragma unroll
        for (int j = 0; j < NCOMP; ++j) off[j] += wsum[w][j];
    }
    #pragma unroll
    for (int j = 0; j < NCOMP; ++j) {
        float e = __shfl_up(inc[j], 1, 64);
        vals[j] = off[j] + ((lane == 0) ? 0.0f : e);
    }
}

__global__ __launch_bounds__(256) void k_scan2(f32x4* __restrict__ a0,
                                               f32x4* __restrict__ a1)
{
    int blk = blockIdx.x, cg = blk & 31, b = blk >> 5;
    int k = threadIdx.x, lane = k & 63, wave = k >> 6;
    size_t o = ((size_t)b * NC + k) * CG + cg;
    f32x4 v0 = a0[o], v1 = a1[o];
    float vals[8] = {v0[0],v0[1],v0[2],v0[3],v1[0],v1[1],v1[2],v1[3]};
    block_exscan<8>(vals, lane, wave);
    a0[o] = (f32x4){vals[0],vals[1],vals[2],vals[3]};
    a1[o] = (f32x4){vals[4],vals[5],vals[6],vals[7]};
}

__global__ __launch_bounds__(256) void k_scan1(f32x4* __restrict__ a0)
{
    int blk = blockIdx.x, cg = blk & 31, b = blk >> 5;
    int k = threadIdx.x, lane = k & 63, wave = k >> 6;
    size_t o = ((size_t)b * NC + k) * CG + cg;
    f32x4 v0 = a0[o];
    float vals[4] = {v0[0],v0[1],v0[2],v0[3]};
    block_exscan<4>(vals, lane, wave);
    a0[o] = (f32x4){vals[0],vals[1],vals[2],vals[3]};
}

// ---------------- P3: per-chunk dev^2 sums ---------------------------------
template <bool BYTES>
__global__ __launch_bounds__(256) void k_pass3(
    const f32x4* __restrict__ x, const f32x4* __restrict__ mask,
    const unsigned* __restrict__ nmb,
    const f32x4* __restrict__ psumx, const f32x4* __restrict__ psumnm,
    f32x4* __restrict__ sumd2)
{
    int gtid = blockIdx.x * 256 + threadIdx.x;
    int b, k, cg; decomp(gtid, b, k, cg);
    size_t base = ((size_t)b * T + (size_t)k * LSUB) * CG + cg;
    size_t o = ((size_t)b * NC + k) * CG + cg;
    f32x4 rx = psumx[o], rn = psumnm[o];
    f32x4 sd = {0,0,0,0};
    #pragma unroll 8
    for (int t = 0; t < LSUB; ++t) {
        f32x4 xv = x[base + (size_t)t * CG];
        f32x4 nm = BYTES ? decode_nm(nmb[base + (size_t)t * CG])
                         : (1.0f - mask[base + (size_t)t * CG]);
        rx += xv; rn += nm;
        f32x4 mean = rx * rcp4(sel_neff(rn));
        f32x4 d = (xv - mean) * nm;
        sd += d * d;
    }
    sumd2[o] = sd;
}

// ---------------- P5: final normalize + clip (single sweep, NT out) --------
template <bool BYTES>
__global__ __launch_bounds__(256) void k_pass5(
    const f32x4* __restrict__ x, const f32x4* __restrict__ mask,
    const unsigned* __restrict__ nmb,
    const f32x4* __restrict__ psumx, const f32x4* __restrict__ psumnm,
    const f32x4* __restrict__ psumd2, f32x4* __restrict__ out)
{
    int gtid = blockIdx.x * 256 + threadIdx.x;
    int b, k, cg; decomp(gtid, b, k, cg);
    size_t base = ((size_t)b * T + (size_t)k * LSUB) * CG + cg;
    size_t o = ((size_t)b * NC + k) * CG + cg;
    f32x4 rx = psumx[o], rn = psumnm[o], rd = psumd2[o];
    #pragma unroll 8
    for (int t = 0; t < LSUB; ++t) {
        f32x4 xv = x[base + (size_t)t * CG];
        f32x4 nm = BYTES ? decode_nm(nmb[base + (size_t)t * CG])
                         : (1.0f - mask[base + (size_t)t * CG]);
        rx += xv; rn += nm;
        f32x4 inv = rcp4(sel_neff(rn));
        f32x4 mean = rx * inv;
        f32x4 d = (xv - mean) * nm;
        rd += d * d;
        f32x4 s = sqrt4(rd * inv);
        f32x4 ov;
        #pragma unroll
        for (int j = 0; j < 4; ++j) {
            float invs = (s[j] > STD_MIN) ? __builtin_amdgcn_rcpf(s[j]) : 1.0f;
            float v = (xv[j] - mean[j]) * invs;
            ov[j] = fminf(fmaxf(v, -MAX_VAL), MAX_VAL);
        }
        __builtin_nontemporal_store(ov, &out[base + (size_t)t * CG]);
    }
}

template <bool BYTES>
static void run_all(const f32x4* x, const f32x4* mask, f32x4* out,
                    void* d_ws, hipStream_t stream)
{
    size_t arr_elems = (size_t)B * NC * C;   // floats per scan array
    f32x4* sumx  = (f32x4*)d_ws;
    f32x4* sumnm = (f32x4*)((float*)d_ws + arr_elems);
    f32x4* sumd2 = (f32x4*)((float*)d_ws + 2 * arr_elems);
    unsigned* nmb = (unsigned*)((float*)d_ws + 3 * arr_elems);

    int main_blocks = B * NC * CG / 256;  // 512
    int scan_blocks = B * CG;             // 512

    k_pass1<BYTES><<<main_blocks, 256, 0, stream>>>(x, mask, sumx, sumnm, nmb);
    k_scan2<<<scan_blocks, 256, 0, stream>>>(sumx, sumnm);
    k_pass3<BYTES><<<main_blocks, 256, 0, stream>>>(x, mask, nmb, sumx, sumnm, sumd2);
    k_scan1<<<scan_blocks, 256, 0, stream>>>(sumd2);
    k_pass5<BYTES><<<main_blocks, 256, 0, stream>>>(x, mask, nmb, sumx, sumnm, sumd2, out);
}

extern "C" void kernel_launch(void* const* d_in, const int* in_sizes, int n_in,
                              void* d_out, int out_size, void* d_ws, size_t ws_size,
                              hipStream_t stream) {
    const f32x4* x    = (const f32x4*)d_in[0];
    const f32x4* mask = (const f32x4*)d_in[1];
    f32x4* out = (f32x4*)d_out;

    size_t need = 3ull * B * NC * C * sizeof(float)      // 6 MiB scan arrays
                + (size_t)B * T * CG * sizeof(unsigned); // 16 MiB nm bytes

    if (ws_size >= need) run_all<true >(x, mask, out, d_ws, stream);
    else                 run_all<false>(x, mask, out, d_ws, stream);
}